// Round 9
// baseline (298.471 us; speedup 1.0000x reference)
//
#include <hip/hip_runtime.h>
#include <math.h>

#define B 2
#define S 1024
#define E 2048
#define H 16
#define HD 128
#define ROT 64
#define EPSN 1e-12f

using half8 = __attribute__((ext_vector_type(8))) _Float16;
using half4 = __attribute__((ext_vector_type(4))) _Float16;
using half2 = __attribute__((ext_vector_type(2))) _Float16;
using f32x4 = __attribute__((ext_vector_type(4))) float;

// async global->LDS, 16B per lane; LDS dest = wave-uniform base + lane*16
__device__ __forceinline__ void gl_lds16(const void* g, void* l) {
    __builtin_amdgcn_global_load_lds(
        (const __attribute__((address_space(1))) unsigned int*)g,
        (__attribute__((address_space(3))) unsigned int*)l, 16, 0, 0);
}

#define BARX()  asm volatile("s_barrier" ::: "memory")
#define LGKM0() asm volatile("s_waitcnt lgkmcnt(0)" ::: "memory")
#define VMW(n)  asm volatile("s_waitcnt vmcnt(" #n ")" ::: "memory")

// Ct swizzle: fp16 [256][256] overlay, half4 granules.
__device__ __forceinline__ int ctIdx(int row, int col) {
    int f = (row & 15) ^ ((row >> 3) & 15);
    return row * 256 + (col & 3) + (((col >> 2) ^ f) << 2);
}

// ---------------------------------------------------------------------------
// prep: (a) fp32->fp16 of 5 tensors — now 2560 FAT blocks (8 float4/thread,
// coalesced) instead of 20480 tiny blocks (block-dispatch-rate bound);
// (b) parallel sincos rotary table; (c) mask prefix counts.
// ---------------------------------------------------------------------------
__global__ __launch_bounds__(256) void prep(const float* __restrict__ x0,
                                            const float* __restrict__ x1,
                                            const float* __restrict__ x2,
                                            const float* __restrict__ x3,
                                            const float* __restrict__ x4,
                                            _Float16* __restrict__ y0,
                                            _Float16* __restrict__ y1,
                                            _Float16* __restrict__ y2,
                                            _Float16* __restrict__ y3,
                                            _Float16* __restrict__ y4,
                                            const float* __restrict__ am,
                                            const int*  __restrict__ pos,
                                            float* __restrict__ cnt,
                                            float* __restrict__ tab) {
    __shared__ float ls[256];
    const int bx = (int)blockIdx.x;
    if (bx < 2560) {                        // 5 x 512 convert blocks
        const float* xs[5] = {x0, x1, x2, x3, x4};
        _Float16*    ys[5] = {y0, y1, y2, y3, y4};
        const int t   = bx >> 9;            // tensor
        const int blk = bx & 511;
        const float4* src = (const float4*)xs[t];
        half4*        dst = (half4*)ys[t];
        const int base = blk * 2048 + (int)threadIdx.x;
#pragma unroll
        for (int k = 0; k < 8; ++k) {
            float4 v = src[base + k * 256];
            half4 h;
            h[0] = (_Float16)v.x; h[1] = (_Float16)v.y;
            h[2] = (_Float16)v.z; h[3] = (_Float16)v.w;
            dst[base + k * 256] = h;
        }
    } else if (bx < 2816) {                 // 256 table blocks: one entry each
        int item = (bx - 2560) * 256 + threadIdx.x;    // 0..65535
        int bs = item >> 5, j = item & 31;
        float p = (float)pos[bs];
        float ang = p * expf(-0.28782313662425574f * (float)j); // ln(1e4)/32
        float s_, c_;
        sincosf(ang, &s_, &c_);
        tab[(size_t)bs * 64 + j * 2]     = c_;
        tab[(size_t)bs * 64 + j * 2 + 1] = s_;
    } else {                                // B scan blocks (256 thr x 4 vals)
        const int b = bx - 2816;
        const int t = threadIdx.x;
        float v[4];
        float s4 = 0.f;
#pragma unroll
        for (int i = 0; i < 4; ++i) {
            v[i] = (am[b * S + t * 4 + i] == 0.f) ? 1.f : 0.f;
            s4 += v[i];
        }
        ls[t] = s4;
        __syncthreads();
        for (int off = 1; off < 256; off <<= 1) {
            float u = (t >= off) ? ls[t - off] : 0.f;
            __syncthreads();
            ls[t] += u;
            __syncthreads();
        }
        float run = ls[t] - s4;             // exclusive base
#pragma unroll
        for (int i = 0; i < 4; ++i) {
            run += v[i];
            cnt[b * S + t * 4 + i] = run;
        }
    }
}

// ---------------------------------------------------------------------------
// Fused QKV NT-GEMM, 256x256 tile, BK=64, round-2 PROVEN 8-phase schedule.
// (byte-identical to round 8 — verified at 90.5 us)
// ---------------------------------------------------------------------------
__global__ __launch_bounds__(512, 2) void gemm_qkv256(
        const _Float16* __restrict__ hs,
        const _Float16* __restrict__ wq,
        const _Float16* __restrict__ wk,
        const _Float16* __restrict__ wv,
        _Float16* __restrict__ qo,
        _Float16* __restrict__ ko,
        _Float16* __restrict__ vto,
        const float* __restrict__ am,
        const float* __restrict__ nc,
        const float* __restrict__ cnt,
        const float* __restrict__ tab) {
    __shared__ uint4 L[8][1024];                 // 128 KiB
    __shared__ float sclA[256], sclB[256];

    const int lid = (int)blockIdx.x;             // 0..191
    const int swz = (lid & 7) * 24 + (lid >> 3); // XCD k gets 24 contiguous ids
    const int z   = swz >> 6;                    // 0..2 matrix
    const int gm  = (swz & 63) >> 3;             // 0..7 m-tile
    const int gn  = swz & 7;                     // 0..7 n-tile
    const _Float16* Asrc = (z == 2) ? wv : hs;
    const _Float16* Bsrc = (z == 2) ? hs : ((z == 0) ? wq : wk);
    const int mBase = gm << 8;
    const int nBase = gn << 8;

    const int tid   = (int)threadIdx.x;
    const int lane  = tid & 63;
    const int w     = tid >> 6;
    const int l15   = lane & 15;
    const int lq    = lane >> 4;
    const int wm4   = (w >> 2) << 2;
    const int wn2   = (w & 3) << 1;
    const int wbase = tid & 448;

    // per-row (z<2) / per-s-col (z=2) scale factors
    if (tid < 256) {
        if (z == 2) {
            const int bbv  = nBase >> 10;
            const int sgx  = (nBase & (S - 1)) + tid;
            const int h0v  = mBase >> 7;
            float valid = (am[bbv * S + sgx] == 0.f) ? 1.f : 0.f;
            float c  = cnt[bbv * S + sgx];
            float g0 = 1.f / (1.f + expf(-nc[h0v]));
            float g1 = 1.f / (1.f + expf(-nc[h0v + 1]));
            sclA[tid] = valid / fmaxf(powf(c, g0), 1.f);
            sclB[tid] = valid / fmaxf(powf(c, g1), 1.f);
        } else {
            const int bb  = mBase >> 10;
            const int sgx = (mBase & (S - 1)) + tid;
            sclA[tid] = (am[bb * S + sgx] == 0.f) ? 1.f : 0.f;
        }
    }

    f32x4 acc[2][2][4][2];
#pragma unroll
    for (int X = 0; X < 2; ++X)
#pragma unroll
        for (int Y = 0; Y < 2; ++Y)
#pragma unroll
            for (int mt = 0; mt < 4; ++mt)
#pragma unroll
                for (int nt = 0; nt < 2; ++nt)
                    acc[X][Y][mt][nt] = (f32x4){0.f, 0.f, 0.f, 0.f};

    half8 af[4][2], wf[2][2];

    auto stage = [&](int slot, const _Float16* src, int rowBase, int hf, int kt) {
#pragma unroll
        for (int j = 0; j < 2; ++j) {
            const int c  = (j << 9) + tid;
            const int rb = c >> 7;
            const int q  = (c >> 4) & 7;
            const int r  = c & 15;
            gl_lds16(&src[(size_t)(rowBase + hf * 128 + rb * 16 + r) * E +
                          kt * 64 + q * 8],
                     &L[slot][(j << 9) + wbase]);
        }
    };
    auto ldsA = [&](int db, int X) {         // slot = db*2+X
#pragma unroll
        for (int mt = 0; mt < 4; ++mt)
#pragma unroll
            for (int ks = 0; ks < 2; ++ks)
                af[mt][ks] = *(const half8*)&L[db * 2 + X]
                    [(wm4 + mt) * 128 + (ks * 4 + lq) * 16 + l15];
    };
    auto ldsB = [&](int db, int Y) {         // slot = 4+db*2+Y
#pragma unroll
        for (int nt = 0; nt < 2; ++nt)
#pragma unroll
            for (int ks = 0; ks < 2; ++ks)
                wf[nt][ks] = *(const half8*)&L[4 + db * 2 + Y]
                    [(wn2 + nt) * 128 + (ks * 4 + lq) * 16 + l15];
    };
    auto mma = [&](int X, int Y) {
        __builtin_amdgcn_s_setprio(1);
#pragma unroll
        for (int mt = 0; mt < 4; ++mt)
#pragma unroll
            for (int nt = 0; nt < 2; ++nt)
#pragma unroll
                for (int ks = 0; ks < 2; ++ks)
                    acc[X][Y][mt][nt] = __builtin_amdgcn_mfma_f32_16x16x32_f16(
                        af[mt][ks], wf[nt][ks], acc[X][Y][mt][nt], 0, 0, 0);
        __builtin_amdgcn_s_setprio(0);
    };

    // prologue: tile0 -> dbuf0 (all 4 halves); tile1 -> dbuf1 {A0,B1,A1}
    stage(0, Asrc, mBase, 0, 0);
    stage(4, Bsrc, nBase, 0, 0);
    stage(1, Asrc, mBase, 1, 0);
    stage(5, Bsrc, nBase, 1, 0);
    stage(2, Asrc, mBase, 0, 1);
    stage(7, Bsrc, nBase, 1, 1);
    stage(3, Asrc, mBase, 1, 1);
    VMW(6);
    BARX();

    for (int j = 0; j < 16; ++j) {
        const int tB  = 2 * j + 1;
        const int tN0 = 2 * j + 2;
        const int tN1 = 2 * j + 3;
        const bool more = (j < 15);

        // ph0: Q(0,0) dbuf0 | stage slot6<-B0 of tile 2j+1
        ldsA(0, 0); ldsB(0, 0);
        stage(6, Bsrc, nBase, 0, tB);
        BARX(); LGKM0();
        mma(0, 0);
        BARX();

        // ph1: Q(0,1) dbuf0 | stage slot0<-A0 tile 2j+2
        ldsB(0, 1);
        if (more) stage(0, Asrc, mBase, 0, tN0);
        BARX(); LGKM0();
        mma(0, 1);
        BARX();

        // ph2: Q(1,1) dbuf0 | stage slot5<-B1 tile 2j+2
        ldsA(0, 1);
        if (more) stage(5, Bsrc, nBase, 1, tN0);
        BARX(); LGKM0();
        mma(1, 1);
        BARX();

        // ph3: Q(1,0) dbuf0 | stage slot1<-A1 | counted vmcnt
        ldsB(0, 0);
        if (more) { stage(1, Asrc, mBase, 1, tN0); VMW(4); }
        else      { VMW(0); }
        BARX(); LGKM0();
        mma(1, 0);
        BARX();

        // ph4: Q(0,0) dbuf1 | stage slot4<-B0 tile 2j+2
        ldsA(1, 0); ldsB(1, 0);
        if (more) stage(4, Bsrc, nBase, 0, tN0);
        BARX(); LGKM0();
        mma(0, 0);
        BARX();

        // ph5: Q(0,1) dbuf1 | stage slot2<-A0 tile 2j+3
        ldsB(1, 1);
        if (more) stage(2, Asrc, mBase, 0, tN1);
        BARX(); LGKM0();
        mma(0, 1);
        BARX();

        // ph6: Q(1,1) dbuf1 | stage slot7<-B1 tile 2j+3
        ldsA(1, 1);
        if (more) stage(7, Bsrc, nBase, 1, tN1);
        BARX(); LGKM0();
        mma(1, 1);
        BARX();

        // ph7: Q(1,0) dbuf1 | stage slot3<-A1 | counted vmcnt
        ldsB(1, 0);
        if (more) stage(3, Asrc, mBase, 1, tN1);
        VMW(4);
        BARX(); LGKM0();
        mma(1, 0);
        BARX();
    }

    if (z < 2) {
        // ---- Q/K epilogue: LDS bounce + rotary + L2-norm + mask ----
        const int bb  = mBase >> 10;
        const int sB0 = mBase & (S - 1);
        const int h0  = nBase >> 7;          // = gn*2
        VMW(0);
        BARX();
        _Float16* CtH = (_Float16*)&L[0][0];
#pragma unroll
        for (int X = 0; X < 2; ++X)
#pragma unroll
            for (int Y = 0; Y < 2; ++Y)
#pragma unroll
                for (int mt = 0; mt < 4; ++mt)
#pragma unroll
                    for (int nt = 0; nt < 2; ++nt)
#pragma unroll
                        for (int r = 0; r < 4; ++r) {
                            int row = X * 128 + (w >> 2) * 64 + mt * 16 + lq * 4 + r;
                            int col = Y * 128 + (w & 3) * 32 + nt * 16 + l15;
                            CtH[ctIdx(row, col)] = (_Float16)acc[X][Y][mt][nt][r];
                        }
        __syncthreads();

        // per-thread row: thread = (row, head); table rotary, local norm
        const int row = tid >> 1;
        const int hh  = tid & 1;
        const int sg  = sB0 + row;
        const float* tb = &tab[((size_t)bb * S + sg) * 64];  // 32 x (cos,sin)

        half4 gv[32];
        float ss = 0.f;
#pragma unroll
        for (int k = 0; k < 32; ++k) {
            half4 x = *(const half4*)&CtH[ctIdx(row, hh * 128 + k * 4)];
            float v0 = x[0], v1 = x[1], v2 = x[2], v3 = x[3];
            if (k < 16) {   // rotary on first 64 elems
                float4 t4 = *(const float4*)&tb[k * 4];
                float t0 = v0 * t4.x - v1 * t4.y;
                float t1 = v1 * t4.x + v0 * t4.y;
                float t2 = v2 * t4.z - v3 * t4.w;
                float t3 = v3 * t4.z + v2 * t4.w;
                v0 = t0; v1 = t1; v2 = t2; v3 = t3;
            }
            ss += v0 * v0 + v1 * v1 + v2 * v2 + v3 * v3;
            half4 y;
            y[0] = (_Float16)v0; y[1] = (_Float16)v1;
            y[2] = (_Float16)v2; y[3] = (_Float16)v3;
            gv[k] = y;
        }
        float scl = sclA[row] / fmaxf(sqrtf(ss), EPSN);
        _Float16* rowOut = (z == 0) ? qo : ko;
        _Float16* gp = &rowOut[(((size_t)bb * H + h0 + hh) * S + sg) * HD];
#pragma unroll
        for (int k = 0; k < 32; ++k) {
            half4 y;
            y[0] = (_Float16)((float)gv[k][0] * scl);
            y[1] = (_Float16)((float)gv[k][1] * scl);
            y[2] = (_Float16)((float)gv[k][2] * scl);
            y[3] = (_Float16)((float)gv[k][3] * scl);
            *(half4*)&gp[k * 4] = y;
        }
    } else {
        // ---- V epilogue: scale -> swizzled LDS tile -> coalesced stores ----
        const int bbv  = nBase >> 10;
        const int sB0v = nBase & (S - 1);
        const int h0v  = mBase >> 7;
        VMW(0);
        BARX();
        _Float16* CtH = (_Float16*)&L[0][0];
#pragma unroll
        for (int X = 0; X < 2; ++X)
#pragma unroll
            for (int Y = 0; Y < 2; ++Y)
#pragma unroll
                for (int mt = 0; mt < 4; ++mt)
#pragma unroll
                    for (int nt = 0; nt < 2; ++nt)
#pragma unroll
                        for (int r = 0; r < 4; ++r) {
                            int row = X * 128 + (w >> 2) * 64 + mt * 16 + lq * 4 + r;
                            int col = Y * 128 + (w & 3) * 32 + nt * 16 + l15;
                            float scl = X ? sclB[col] : sclA[col];
                            CtH[ctIdx(row, col)] =
                                (_Float16)(acc[X][Y][mt][nt][r] * scl);
                        }
        __syncthreads();
        // row-major readout: tile is already [dv][s]; 512B-coalesced stores
#pragma unroll
        for (int i = 0; i < 16; ++i) {
            int f  = tid + i * 512;
            int dr = f >> 5;            // dv row 0..255 (2 heads x 128 d)
            int sc = f & 31;            // 8-s chunk
            half4 a = *(const half4*)&CtH[ctIdx(dr, sc * 8)];
            half4 b = *(const half4*)&CtH[ctIdx(dr, sc * 8 + 4)];
            half8 hv;
            hv[0] = a[0]; hv[1] = a[1]; hv[2] = a[2]; hv[3] = a[3];
            hv[4] = b[0]; hv[5] = b[1]; hv[6] = b[2]; hv[7] = b[3];
            *(half8*)&vto[((size_t)(bbv * H + h0v + (dr >> 7)) * HD +
                           (dr & 127)) * S + sB0v + sc * 8] = hv;
        }
    }
}

// ---------------------------------------------------------------------------
// kvp: fused kvouter + prefix (verified r6). Grid (4 dv-slices, 32 bh).
// ---------------------------------------------------------------------------
__global__ __launch_bounds__(256) void kvp(const _Float16* __restrict__ kh,
                                           const _Float16* __restrict__ vt,
                                           _Float16* __restrict__ ut) {
    __shared__ _Float16 Kt_s[HD][72];    // [d][s] pad 8 -> frag reads 2-way
    __shared__ _Float16 Vt_s[32][72];
    const int slice = blockIdx.x;        // 0..3 (32 dv each)
    const int bh    = blockIdx.y;
    const int tid = threadIdx.x;
    const int lane = tid & 63, w = tid >> 6;
    const int l15 = lane & 15, lq = lane >> 4;
    const size_t kbase = (size_t)bh * S * HD;
    const size_t vbase = ((size_t)bh * HD + slice * 32) * S;

    f32x4 accr[2][2];
#pragma unroll
    for (int mt = 0; mt < 2; ++mt)
#pragma unroll
        for (int nt = 0; nt < 2; ++nt)
            accr[mt][nt] = (f32x4){0.f, 0.f, 0.f, 0.f};

    for (int c = 0; c < 16; ++c) {
        const int c0 = c * 64;
        half8 kreg[4];
#pragma unroll
        for (int j = 0; j < 4; ++j)
            kreg[j] = *(const half8*)&kh[kbase + (size_t)(c0 + lane) * HD +
                                         (j * 4 + w) * 8];
        uint4 vreg = *(const uint4*)&vt[vbase + (size_t)(tid >> 3) * S +
                                        c0 + (tid & 7) * 8];

        // M_c = exclusive running prefix (register state; overlaps loads)
        const size_t ub = ((size_t)bh * 16 + c) << 14;
#pragma unroll
        for (int mt = 0; mt < 2; ++mt)
#pragma unroll
            for (int nt = 0; nt < 2; ++nt) {
                int mtg = w * 2 + mt, ntg = slice * 2 + nt;
                int f0 = ntg * 2048 + (mtg >> 1) * 512 +
                         (l15 + ((mtg * 2 + (lq >> 1)) & 3) * 16) * 8 +
                         (lq & 1) * 4;
                half4 hv;
                hv[0] = (_Float16)accr[mt][nt][0];
                hv[1] = (_Float16)accr[mt][nt][1];
                hv[2] = (_Float16)accr[mt][nt][2];
                hv[3] = (_Float16)accr[mt][nt][3];
                *(half4*)&ut[ub + f0] = hv;
            }

        __syncthreads();   // prior chunk's frag reads complete
#pragma unroll
        for (int j = 0; j < 4; ++j)
#pragma unroll
            for (int i = 0; i < 8; ++i)
                Kt_s[(j * 4 + w) * 8 + i][lane] = kreg[j][i];
        *(uint4*)&Vt_s[tid >> 3][(tid & 7) * 8] = vreg;
        __syncthreads();

#pragma unroll
        for (int ks = 0; ks < 2; ++ks) {
            half8 afv[2], wfv[2];
#pragma unroll
            for (int mt = 0; mt < 2; ++mt)
                afv[mt] = *(const half8*)&Kt_s[(w * 2 + mt) * 16 + l15]
                                              [ks * 32 + lq * 8];
#pragma unroll
            for (int nt = 0; nt < 2; ++nt)
                wfv[nt] = *(const half8*)&Vt_s[nt * 16 + l15][ks * 32 + lq * 8];
#pragma unroll
            for (int mt = 0; mt < 2; ++mt)
#pragma unroll
                for (int nt = 0; nt < 2; ++nt)
                    accr[mt][nt] = __builtin_amdgcn_mfma_f32_16x16x32_f16(
                        afv[mt], wfv[nt], accr[mt][nt], 0, 0, 0);
        }
    }
}

// ---------------------------------------------------------------------------
// attn_local: O_tile = Q_tile . M^T_qt + tril(Q_tile K_qt^T) V_qt (verified).
// ---------------------------------------------------------------------------
__global__ __launch_bounds__(256) void attn_local(const _Float16* __restrict__ qh,
                                                  const _Float16* __restrict__ kh,
                                                  const _Float16* __restrict__ vt,
                                                  const _Float16* __restrict__ mt,
                                                  _Float16* __restrict__ o) {
    __shared__ _Float16 Ks[64][136];
    __shared__ _Float16 Vs[HD][72];
    __shared__ _Float16 Ps[64][72];
    __shared__ uint4 Ms[2048];

    const int qt = blockIdx.x;
    const int bh = blockIdx.y;
    const int b = bh >> 4, h = bh & 15;
    const int tid = threadIdx.x;
    const int lane = tid & 63;
    const int w = tid >> 6;
    const int l15 = lane & 15;
    const int lq = lane >> 4;
    const int qBase = qt * 64;
    const size_t sd_base = (size_t)bh * S * HD;

    half8 qf[4];
#pragma unroll
    for (int ks = 0; ks < 4; ++ks)
        qf[ks] = *(const half8*)&qh[sd_base + (size_t)(qBase + w * 16 + l15) * HD +
                                    ks * 32 + lq * 8];

    const _Float16* mtc = mt + (((size_t)bh * 16 + qt) << 14);
#pragma unroll
    for (int rr = 0; rr < 8; ++rr)
        gl_lds16(&mtc[(size_t)((rr * 4 + w) * 64 + lane) * 8],
                 &Ms[(rr * 4 + w) * 64]);

    uint4 pk[4], pv[4];
#pragma unroll
    for (int j = 0; j < 4; ++j) {
        int f = tid + j * 256;
        int rK = f >> 4, c8K = f & 15;
        int rV = f >> 3, c8V = f & 7;
        pk[j] = *(const uint4*)&kh[sd_base + (size_t)(qBase + rK) * HD + c8K * 8];
        pv[j] = *(const uint4*)&vt[sd_base + (size_t)rV * S + qBase + c8V * 8];
    }
#pragma unroll
    for (int j = 0; j < 4; ++j) {
        int f = tid + j * 256;
        int rK = f >> 4, c8K = f & 15;
        int rV = f >> 3, c8V = f & 7;
        *(uint4*)&Ks[rK][c8K * 8] = pk[j];
        *(uint4*)&Vs[rV][c8V * 8] = pv[j];
    }
    __syncthreads();

    f32x4 sacc[4];
#pragma unroll
    for (int nt = 0; nt < 4; ++nt)
        sacc[nt] = (f32x4){0.f, 0.f, 0.f, 0.f};
#pragma unroll
    for (int nt = 0; nt < 4; ++nt)
#pragma unroll
        for (int ks = 0; ks < 4; ++ks) {
            half8 kf = *(const half8*)&Ks[nt * 16 + l15][ks * 32 + lq * 8];
            sacc[nt] = __builtin_amdgcn_mfma_f32_16x16x32_f16(qf[ks], kf,
                                                              sacc[nt], 0, 0, 0);
        }

#pragma unroll
    for (int nt = 0; nt < 4; ++nt)
#pragma unroll
        for (int r = 0; r < 4; ++r) {
            int ql = w * 16 + lq * 4 + r;
            int kl = nt * 16 + l15;
            float sv = (kl <= ql) ? sacc[nt][r] : 0.f;
            Ps[ql][kl] = (_Float16)sv;
        }

    f32x4 oacc[8];
#pragma unroll
    for (int dt = 0; dt < 8; ++dt)
        oacc[dt] = (f32x4){0.f, 0.f, 0.f, 0.f};
#pragma unroll
    for (int dt = 0; dt < 8; ++dt)
#pragma unroll
        for (int km = 0; km < 4; ++km) {
            half8 mf = *(const half8*)&Ms[(dt * 4 + km) * 64 + lane];
            oacc[dt] = __builtin_amdgcn_mfma_f32_16x16x32_f16(qf[km], mf,
                                                              oacc[dt], 0, 0, 0);
        }
    __syncthreads();

    half8 pf[2];
    pf[0] = *(const half8*)&Ps[w * 16 + l15][lq * 8];
    pf[1] = *(const half8*)&Ps[w * 16 + l15][32 + lq * 8];
#pragma unroll
    for (int dt = 0; dt < 8; ++dt)
#pragma unroll
        for (int ks = 0; ks < 2; ++ks) {
            half8 vf = *(const half8*)&Vs[dt * 16 + l15][ks * 32 + lq * 8];
            oacc[dt] = __builtin_amdgcn_mfma_f32_16x16x32_f16(pf[ks], vf,
                                                              oacc[dt], 0, 0, 0);
        }

#pragma unroll
    for (int dt = 0; dt < 8; ++dt)
#pragma unroll
        for (int r = 0; r < 4; ++r)
            Ks[w * 16 + lq * 4 + r][dt * 16 + l15] = (_Float16)oacc[dt][r];
    __syncthreads();
#pragma unroll
    for (int j = 0; j < 4; ++j) {
        int f = tid + j * 256;
        int ql = f >> 4, c8 = f & 15;
        *(uint4*)&o[(size_t)(b * S + qBase + ql) * E + h * HD + c8 * 8] =
            *(const uint4*)&Ks[ql][c8 * 8];
    }
}

// ---------------------------------------------------------------------------
// Out-projection NT-GEMM, 128x128, double-buffered, BK=64 (was 32): halves
// the barrier count (64 -> 32 iters). LDS 64 KB; [rb][q][r] chunk layout and
// frag formulas identical to gemm_qkv256's proven half-tile.
// ---------------------------------------------------------------------------
__global__ __launch_bounds__(256) void gemm_out(const _Float16* __restrict__ A,
                                                const _Float16* __restrict__ Wp,
                                                float* __restrict__ C) {
    __shared__ uint4 As_l[2][1024];   // 2 x 16 KB
    __shared__ uint4 Ws_l[2][1024];   // 2 x 16 KB
    const int lid = (int)blockIdx.x;
    const int swz = (lid & 7) * 32 + (lid >> 3);
    const int gm  = swz >> 4;
    const int gn  = swz & 15;
    const int tid  = threadIdx.x;
    const int lane = tid & 63;
    const int w    = tid >> 6;
    const int wm   = (w >> 1) * 64;
    const int wn   = (w & 1) * 64;
    const int l15  = lane & 15;
    const int lq   = lane >> 4;
    const int mBase = gm * 128;
    const int nBase = gn * 128;
    const int wb64  = tid & 192;      // wave-uniform chunk base within 256

    f32x4 acc[4][4];
#pragma unroll
    for (int mt = 0; mt < 4; ++mt)
#pragma unroll
        for (int nt = 0; nt < 4; ++nt)
            acc[mt][nt] = (f32x4){0.f, 0.f, 0.f, 0.f};

    auto stage = [&](int bf, int k0) {
#pragma unroll
        for (int j = 0; j < 4; ++j) {
            int c  = j * 256 + tid;          // chunk 0..1023
            int rb = c >> 7;                 // 16-row block 0..7
            int q  = (c >> 4) & 7;           // 16B k-chunk 0..7
            int r  = c & 15;                 // row within block
            gl_lds16(&A[(size_t)(mBase + rb * 16 + r) * E + k0 + q * 8],
                     &As_l[bf][j * 256 + wb64]);
        }
#pragma unroll
        for (int j = 0; j < 4; ++j) {
            int c  = j * 256 + tid;
            int rb = c >> 7;
            int q  = (c >> 4) & 7;
            int r  = c & 15;
            gl_lds16(&Wp[(size_t)(nBase + rb * 16 + r) * E + k0 + q * 8],
                     &Ws_l[bf][j * 256 + wb64]);
        }
    };

    stage(0, 0);
    const int nIter = E / 64;                 // 32
    for (int it = 0; it < nIter; ++it) {
        __syncthreads();
        if (it + 1 < nIter) stage((it + 1) & 1, (it + 1) * 64);

        const int cur = it & 1;
        half8 af[4][2], wfr[4][2];
#pragma unroll
        for (int t = 0; t < 4; ++t)
#pragma unroll
            for (int ks = 0; ks < 2; ++ks) {
                int rbA = (wm >> 4) + t;
                int rbW = (wn >> 4) + t;
                af[t][ks]  = *(const half8*)&As_l[cur]
                    [rbA * 128 + (ks * 4 + lq) * 16 + l15];
                wfr[t][ks] = *(const half8*)&Ws_l[cur]
                    [rbW * 128 + (ks * 4 + lq) * 16 + l15];
            }
#pragma unroll
        for (int mt = 0; mt < 4; ++mt)
#pragma unroll
            for (int nt = 0; nt < 4; ++nt)
#pragma unroll
                for (int ks = 0; ks < 2; ++ks)
                    acc[mt][nt] = __builtin_amdgcn_mfma_f32_16x16x32_f16(
                        af[mt][ks], wfr[nt][ks], acc[mt][nt], 0, 0, 0);
    }

#pragma unroll
    for (int mt = 0; mt < 4; ++mt)
#pragma unroll
        for (int nt = 0; nt < 4; ++nt)
#pragma unroll
            for (int r = 0; r < 4; ++r) {
                int row = mBase + wm + mt * 16 + lq * 4 + r;
                int col = nBase + wn + nt * 16 + l15;
                C[(size_t)row * E + col] = acc[mt][nt][r];
            }
}

// ---------------------------------------------------------------------------
extern "C" void kernel_launch(void* const* d_in, const int* in_sizes, int n_in,
                              void* d_out, int out_size, void* d_ws, size_t ws_size,
                              hipStream_t stream) {
    (void)in_sizes; (void)n_in; (void)out_size; (void)ws_size;
    const float* hs = (const float*)d_in[0];
    const float* wq = (const float*)d_in[1];
    const float* wk = (const float*)d_in[2];
    const float* wv = (const float*)d_in[3];
    const float* wo = (const float*)d_in[4];
    const float* nc = (const float*)d_in[5];
    const float* am = (const float*)d_in[6];
    const int*  pos = (const int*)d_in[7];
    float* out = (float*)d_out;

    const size_t act = (size_t)B * S * E;           // 4,194,304 (== E*E)
    _Float16* hsb = (_Float16*)d_ws;                // fp16 copies
    _Float16* wqb = hsb + act;
    _Float16* wkb = wqb + act;
    _Float16* wvb = wkb + act;
    _Float16* wob = wvb + act;
    _Float16* qhh = wob + act;                      // Q (b,h,s,d)
    _Float16* khh = qhh + act;                      // K (b,h,s,d)
    _Float16* vtt = khh + act;                      // V^T (b,h,d,s)
    _Float16* abb = vtt + act;                      // attn out (b,s,E)
    _Float16* utm = wqb;                            // M frag-major (2 slots)
    float*    cnt = (float*)abb;                    // prefix counts (pre-attn)
    float*    tab = cnt + B * S;                    // rotary table, 512 KB
    // total ws: 9 * 8.39MB ~= 76 MB

    prep<<<2816 + B, 256, 0, stream>>>(
        hs, wq, wk, wv, wo, hsb, wqb, wkb, wvb, wob, am, pos, cnt, tab);

    gemm_qkv256<<<192, 512, 0, stream>>>(hsb, wqb, wkb, wvb,
                                         qhh, khh, vtt, am, nc, cnt, tab);

    kvp<<<dim3(4, B * H), 256, 0, stream>>>(khh, vtt, utm);

    attn_local<<<dim3(16, B * H), 256, 0, stream>>>(qhh, khh, vtt, utm, abb);

    gemm_out<<<256, 256, 0, stream>>>(abb, wob, out);
}

// Round 10
// 294.197 us; speedup vs baseline: 1.0145x; 1.0145x over previous
//
#include <hip/hip_runtime.h>
#include <math.h>

#define B 2
#define S 1024
#define E 2048
#define H 16
#define HD 128
#define ROT 64
#define EPSN 1e-12f

using half8 = __attribute__((ext_vector_type(8))) _Float16;
using half4 = __attribute__((ext_vector_type(4))) _Float16;
using half2 = __attribute__((ext_vector_type(2))) _Float16;
using f32x4 = __attribute__((ext_vector_type(4))) float;

// async global->LDS, 16B per lane; LDS dest = wave-uniform base + lane*16
__device__ __forceinline__ void gl_lds16(const void* g, void* l) {
    __builtin_amdgcn_global_load_lds(
        (const __attribute__((address_space(1))) unsigned int*)g,
        (__attribute__((address_space(3))) unsigned int*)l, 16, 0, 0);
}

#define BARX()  asm volatile("s_barrier" ::: "memory")
#define LGKM0() asm volatile("s_waitcnt lgkmcnt(0)" ::: "memory")
#define VMW(n)  asm volatile("s_waitcnt vmcnt(" #n ")" ::: "memory")

// Ct swizzle: fp16 [256][256] overlay, half4 granules.
__device__ __forceinline__ int ctIdx(int row, int col) {
    int f = (row & 15) ^ ((row >> 3) & 15);
    return row * 256 + (col & 3) + (((col >> 2) ^ f) << 2);
}

// ---------------------------------------------------------------------------
// prep: (a) fp32->fp16 of 5 tensors (2560 fat blocks, 8 float4/thread);
// (b) parallel sincos rotary table; (c) mask prefix counts. (verified r9)
// ---------------------------------------------------------------------------
__global__ __launch_bounds__(256) void prep(const float* __restrict__ x0,
                                            const float* __restrict__ x1,
                                            const float* __restrict__ x2,
                                            const float* __restrict__ x3,
                                            const float* __restrict__ x4,
                                            _Float16* __restrict__ y0,
                                            _Float16* __restrict__ y1,
                                            _Float16* __restrict__ y2,
                                            _Float16* __restrict__ y3,
                                            _Float16* __restrict__ y4,
                                            const float* __restrict__ am,
                                            const int*  __restrict__ pos,
                                            float* __restrict__ cnt,
                                            float* __restrict__ tab) {
    __shared__ float ls[256];
    const int bx = (int)blockIdx.x;
    if (bx < 2560) {                        // 5 x 512 convert blocks
        const float* xs[5] = {x0, x1, x2, x3, x4};
        _Float16*    ys[5] = {y0, y1, y2, y3, y4};
        const int t   = bx >> 9;            // tensor
        const int blk = bx & 511;
        const float4* src = (const float4*)xs[t];
        half4*        dst = (half4*)ys[t];
        const int base = blk * 2048 + (int)threadIdx.x;
#pragma unroll
        for (int k = 0; k < 8; ++k) {
            float4 v = src[base + k * 256];
            half4 h;
            h[0] = (_Float16)v.x; h[1] = (_Float16)v.y;
            h[2] = (_Float16)v.z; h[3] = (_Float16)v.w;
            dst[base + k * 256] = h;
        }
    } else if (bx < 2816) {                 // 256 table blocks: one entry each
        int item = (bx - 2560) * 256 + threadIdx.x;    // 0..65535
        int bs = item >> 5, j = item & 31;
        float p = (float)pos[bs];
        float ang = p * expf(-0.28782313662425574f * (float)j); // ln(1e4)/32
        float s_, c_;
        sincosf(ang, &s_, &c_);
        tab[(size_t)bs * 64 + j * 2]     = c_;
        tab[(size_t)bs * 64 + j * 2 + 1] = s_;
    } else {                                // B scan blocks (256 thr x 4 vals)
        const int b = bx - 2816;
        const int t = threadIdx.x;
        float v[4];
        float s4 = 0.f;
#pragma unroll
        for (int i = 0; i < 4; ++i) {
            v[i] = (am[b * S + t * 4 + i] == 0.f) ? 1.f : 0.f;
            s4 += v[i];
        }
        ls[t] = s4;
        __syncthreads();
        for (int off = 1; off < 256; off <<= 1) {
            float u = (t >= off) ? ls[t - off] : 0.f;
            __syncthreads();
            ls[t] += u;
            __syncthreads();
        }
        float run = ls[t] - s4;             // exclusive base
#pragma unroll
        for (int i = 0; i < 4; ++i) {
            run += v[i];
            cnt[b * S + t * 4 + i] = run;
        }
    }
}

// ---------------------------------------------------------------------------
// Fused QKV NT-GEMM, 256x256 tile, BK=64, round-2 PROVEN 8-phase schedule.
// CHANGE vs r9: counted vmcnt relaxed VMW(4)->VMW(6) (m201 discipline; slot
// lifetimes re-verified: worst case slot6 staged ph0 / read ph4 with exactly
// 6 intervening vmcnt units -> VMW(6) at ph3 completes precisely that stage).
// ---------------------------------------------------------------------------
__global__ __launch_bounds__(512, 2) void gemm_qkv256(
        const _Float16* __restrict__ hs,
        const _Float16* __restrict__ wq,
        const _Float16* __restrict__ wk,
        const _Float16* __restrict__ wv,
        _Float16* __restrict__ qo,
        _Float16* __restrict__ ko,
        _Float16* __restrict__ vto,
        const float* __restrict__ am,
        const float* __restrict__ nc,
        const float* __restrict__ cnt,
        const float* __restrict__ tab) {
    __shared__ uint4 L[8][1024];                 // 128 KiB
    __shared__ float sclA[256], sclB[256];

    const int lid = (int)blockIdx.x;             // 0..191
    const int swz = (lid & 7) * 24 + (lid >> 3); // XCD k gets 24 contiguous ids
    const int z   = swz >> 6;                    // 0..2 matrix
    const int gm  = (swz & 63) >> 3;             // 0..7 m-tile
    const int gn  = swz & 7;                     // 0..7 n-tile
    const _Float16* Asrc = (z == 2) ? wv : hs;
    const _Float16* Bsrc = (z == 2) ? hs : ((z == 0) ? wq : wk);
    const int mBase = gm << 8;
    const int nBase = gn << 8;

    const int tid   = (int)threadIdx.x;
    const int lane  = tid & 63;
    const int w     = tid >> 6;
    const int l15   = lane & 15;
    const int lq    = lane >> 4;
    const int wm4   = (w >> 2) << 2;
    const int wn2   = (w & 3) << 1;
    const int wbase = tid & 448;

    // per-row (z<2) / per-s-col (z=2) scale factors
    if (tid < 256) {
        if (z == 2) {
            const int bbv  = nBase >> 10;
            const int sgx  = (nBase & (S - 1)) + tid;
            const int h0v  = mBase >> 7;
            float valid = (am[bbv * S + sgx] == 0.f) ? 1.f : 0.f;
            float c  = cnt[bbv * S + sgx];
            float g0 = 1.f / (1.f + expf(-nc[h0v]));
            float g1 = 1.f / (1.f + expf(-nc[h0v + 1]));
            sclA[tid] = valid / fmaxf(powf(c, g0), 1.f);
            sclB[tid] = valid / fmaxf(powf(c, g1), 1.f);
        } else {
            const int bb  = mBase >> 10;
            const int sgx = (mBase & (S - 1)) + tid;
            sclA[tid] = (am[bb * S + sgx] == 0.f) ? 1.f : 0.f;
        }
    }

    f32x4 acc[2][2][4][2];
#pragma unroll
    for (int X = 0; X < 2; ++X)
#pragma unroll
        for (int Y = 0; Y < 2; ++Y)
#pragma unroll
            for (int mt = 0; mt < 4; ++mt)
#pragma unroll
                for (int nt = 0; nt < 2; ++nt)
                    acc[X][Y][mt][nt] = (f32x4){0.f, 0.f, 0.f, 0.f};

    half8 af[4][2], wf[2][2];

    auto stage = [&](int slot, const _Float16* src, int rowBase, int hf, int kt) {
#pragma unroll
        for (int j = 0; j < 2; ++j) {
            const int c  = (j << 9) + tid;
            const int rb = c >> 7;
            const int q  = (c >> 4) & 7;
            const int r  = c & 15;
            gl_lds16(&src[(size_t)(rowBase + hf * 128 + rb * 16 + r) * E +
                          kt * 64 + q * 8],
                     &L[slot][(j << 9) + wbase]);
        }
    };
    auto ldsA = [&](int db, int X) {         // slot = db*2+X
#pragma unroll
        for (int mt = 0; mt < 4; ++mt)
#pragma unroll
            for (int ks = 0; ks < 2; ++ks)
                af[mt][ks] = *(const half8*)&L[db * 2 + X]
                    [(wm4 + mt) * 128 + (ks * 4 + lq) * 16 + l15];
    };
    auto ldsB = [&](int db, int Y) {         // slot = 4+db*2+Y
#pragma unroll
        for (int nt = 0; nt < 2; ++nt)
#pragma unroll
            for (int ks = 0; ks < 2; ++ks)
                wf[nt][ks] = *(const half8*)&L[4 + db * 2 + Y]
                    [(wn2 + nt) * 128 + (ks * 4 + lq) * 16 + l15];
    };
    auto mma = [&](int X, int Y) {
        __builtin_amdgcn_s_setprio(1);
#pragma unroll
        for (int mt = 0; mt < 4; ++mt)
#pragma unroll
            for (int nt = 0; nt < 2; ++nt)
#pragma unroll
                for (int ks = 0; ks < 2; ++ks)
                    acc[X][Y][mt][nt] = __builtin_amdgcn_mfma_f32_16x16x32_f16(
                        af[mt][ks], wf[nt][ks], acc[X][Y][mt][nt], 0, 0, 0);
        __builtin_amdgcn_s_setprio(0);
    };

    // prologue: tile0 -> dbuf0 (all 4 halves); tile1 -> dbuf1 {A0,B1,A1}
    stage(0, Asrc, mBase, 0, 0);
    stage(4, Bsrc, nBase, 0, 0);
    stage(1, Asrc, mBase, 1, 0);
    stage(5, Bsrc, nBase, 1, 0);
    stage(2, Asrc, mBase, 0, 1);
    stage(7, Bsrc, nBase, 1, 1);
    stage(3, Asrc, mBase, 1, 1);
    VMW(6);
    BARX();

    for (int j = 0; j < 16; ++j) {
        const int tB  = 2 * j + 1;
        const int tN0 = 2 * j + 2;
        const int tN1 = 2 * j + 3;
        const bool more = (j < 15);

        // ph0: Q(0,0) dbuf0 | stage slot6<-B0 of tile 2j+1
        ldsA(0, 0); ldsB(0, 0);
        stage(6, Bsrc, nBase, 0, tB);
        BARX(); LGKM0();
        mma(0, 0);
        BARX();

        // ph1: Q(0,1) dbuf0 | stage slot0<-A0 tile 2j+2
        ldsB(0, 1);
        if (more) stage(0, Asrc, mBase, 0, tN0);
        BARX(); LGKM0();
        mma(0, 1);
        BARX();

        // ph2: Q(1,1) dbuf0 | stage slot5<-B1 tile 2j+2
        ldsA(0, 1);
        if (more) stage(5, Bsrc, nBase, 1, tN0);
        BARX(); LGKM0();
        mma(1, 1);
        BARX();

        // ph3: Q(1,0) dbuf0 | stage slot1<-A1 | counted vmcnt (6: 3 stages fly)
        ldsB(0, 0);
        if (more) { stage(1, Asrc, mBase, 1, tN0); VMW(6); }
        else      { VMW(0); }
        BARX(); LGKM0();
        mma(1, 0);
        BARX();

        // ph4: Q(0,0) dbuf1 | stage slot4<-B0 tile 2j+2
        ldsA(1, 0); ldsB(1, 0);
        if (more) stage(4, Bsrc, nBase, 0, tN0);
        BARX(); LGKM0();
        mma(0, 0);
        BARX();

        // ph5: Q(0,1) dbuf1 | stage slot2<-A0 tile 2j+3
        ldsB(1, 1);
        if (more) stage(2, Asrc, mBase, 0, tN1);
        BARX(); LGKM0();
        mma(0, 1);
        BARX();

        // ph6: Q(1,1) dbuf1 | stage slot7<-B1 tile 2j+3
        ldsA(1, 1);
        if (more) stage(7, Bsrc, nBase, 1, tN1);
        BARX(); LGKM0();
        mma(1, 1);
        BARX();

        // ph7: Q(1,0) dbuf1 | stage slot3<-A1 | counted vmcnt
        ldsB(1, 0);
        if (more) stage(3, Asrc, mBase, 1, tN1);
        VMW(6);
        BARX(); LGKM0();
        mma(1, 0);
        BARX();
    }

    if (z < 2) {
        // ---- Q/K epilogue: LDS bounce + rotary + L2-norm + mask ----
        const int bb  = mBase >> 10;
        const int sB0 = mBase & (S - 1);
        const int h0  = nBase >> 7;          // = gn*2
        VMW(0);
        BARX();
        _Float16* CtH = (_Float16*)&L[0][0];
#pragma unroll
        for (int X = 0; X < 2; ++X)
#pragma unroll
            for (int Y = 0; Y < 2; ++Y)
#pragma unroll
                for (int mt = 0; mt < 4; ++mt)
#pragma unroll
                    for (int nt = 0; nt < 2; ++nt)
#pragma unroll
                        for (int r = 0; r < 4; ++r) {
                            int row = X * 128 + (w >> 2) * 64 + mt * 16 + lq * 4 + r;
                            int col = Y * 128 + (w & 3) * 32 + nt * 16 + l15;
                            CtH[ctIdx(row, col)] = (_Float16)acc[X][Y][mt][nt][r];
                        }
        __syncthreads();

        // per-thread row: thread = (row, head); table rotary, local norm
        const int row = tid >> 1;
        const int hh  = tid & 1;
        const int sg  = sB0 + row;
        const float* tb = &tab[((size_t)bb * S + sg) * 64];  // 32 x (cos,sin)

        half4 gv[32];
        float ss = 0.f;
#pragma unroll
        for (int k = 0; k < 32; ++k) {
            half4 x = *(const half4*)&CtH[ctIdx(row, hh * 128 + k * 4)];
            float v0 = x[0], v1 = x[1], v2 = x[2], v3 = x[3];
            if (k < 16) {   // rotary on first 64 elems
                float4 t4 = *(const float4*)&tb[k * 4];
                float t0 = v0 * t4.x - v1 * t4.y;
                float t1 = v1 * t4.x + v0 * t4.y;
                float t2 = v2 * t4.z - v3 * t4.w;
                float t3 = v3 * t4.z + v2 * t4.w;
                v0 = t0; v1 = t1; v2 = t2; v3 = t3;
            }
            ss += v0 * v0 + v1 * v1 + v2 * v2 + v3 * v3;
            half4 y;
            y[0] = (_Float16)v0; y[1] = (_Float16)v1;
            y[2] = (_Float16)v2; y[3] = (_Float16)v3;
            gv[k] = y;
        }
        float scl = sclA[row] / fmaxf(sqrtf(ss), EPSN);
        _Float16* rowOut = (z == 0) ? qo : ko;
        _Float16* gp = &rowOut[(((size_t)bb * H + h0 + hh) * S + sg) * HD];
#pragma unroll
        for (int k = 0; k < 32; ++k) {
            half4 y;
            y[0] = (_Float16)((float)gv[k][0] * scl);
            y[1] = (_Float16)((float)gv[k][1] * scl);
            y[2] = (_Float16)((float)gv[k][2] * scl);
            y[3] = (_Float16)((float)gv[k][3] * scl);
            *(half4*)&gp[k * 4] = y;
        }
    } else {
        // ---- V epilogue: scale -> swizzled LDS tile -> coalesced stores ----
        const int bbv  = nBase >> 10;
        const int sB0v = nBase & (S - 1);
        const int h0v  = mBase >> 7;
        VMW(0);
        BARX();
        _Float16* CtH = (_Float16*)&L[0][0];
#pragma unroll
        for (int X = 0; X < 2; ++X)
#pragma unroll
            for (int Y = 0; Y < 2; ++Y)
#pragma unroll
                for (int mt = 0; mt < 4; ++mt)
#pragma unroll
                    for (int nt = 0; nt < 2; ++nt)
#pragma unroll
                        for (int r = 0; r < 4; ++r) {
                            int row = X * 128 + (w >> 2) * 64 + mt * 16 + lq * 4 + r;
                            int col = Y * 128 + (w & 3) * 32 + nt * 16 + l15;
                            float scl = X ? sclB[col] : sclA[col];
                            CtH[ctIdx(row, col)] =
                                (_Float16)(acc[X][Y][mt][nt][r] * scl);
                        }
        __syncthreads();
        // row-major readout: tile is already [dv][s]; 512B-coalesced stores
#pragma unroll
        for (int i = 0; i < 16; ++i) {
            int f  = tid + i * 512;
            int dr = f >> 5;            // dv row 0..255 (2 heads x 128 d)
            int sc = f & 31;            // 8-s chunk
            half4 a = *(const half4*)&CtH[ctIdx(dr, sc * 8)];
            half4 b = *(const half4*)&CtH[ctIdx(dr, sc * 8 + 4)];
            half8 hv;
            hv[0] = a[0]; hv[1] = a[1]; hv[2] = a[2]; hv[3] = a[3];
            hv[4] = b[0]; hv[5] = b[1]; hv[6] = b[2]; hv[7] = b[3];
            *(half8*)&vto[((size_t)(bbv * H + h0v + (dr >> 7)) * HD +
                           (dr & 127)) * S + sB0v + sc * 8] = hv;
        }
    }
}

// ---------------------------------------------------------------------------
// kvp: fused kvouter + prefix. Grid (4 dv-slices, 32 bh).
// CHANGE vs r9: next chunk's K/V global loads issue right after this chunk's
// ds_writes (register WAR safe: ds ops capture operands at issue) so the
// ~900-cycle HBM latency hides under the MFMA + M-writeout instead of
// serializing 16x per block.
// ---------------------------------------------------------------------------
__global__ __launch_bounds__(256) void kvp(const _Float16* __restrict__ kh,
                                           const _Float16* __restrict__ vt,
                                           _Float16* __restrict__ ut) {
    __shared__ _Float16 Kt_s[HD][72];    // [d][s] pad 8 -> frag reads 2-way
    __shared__ _Float16 Vt_s[32][72];
    const int slice = blockIdx.x;        // 0..3 (32 dv each)
    const int bh    = blockIdx.y;
    const int tid = threadIdx.x;
    const int lane = tid & 63, w = tid >> 6;
    const int l15 = lane & 15, lq = lane >> 4;
    const size_t kbase = (size_t)bh * S * HD;
    const size_t vbase = ((size_t)bh * HD + slice * 32) * S;

    f32x4 accr[2][2];
#pragma unroll
    for (int mt = 0; mt < 2; ++mt)
#pragma unroll
        for (int nt = 0; nt < 2; ++nt)
            accr[mt][nt] = (f32x4){0.f, 0.f, 0.f, 0.f};

    // prefetch chunk 0
    half8 kreg[4];
    uint4 vreg;
#pragma unroll
    for (int j = 0; j < 4; ++j)
        kreg[j] = *(const half8*)&kh[kbase + (size_t)lane * HD + (j * 4 + w) * 8];
    vreg = *(const uint4*)&vt[vbase + (size_t)(tid >> 3) * S + (tid & 7) * 8];

    for (int c = 0; c < 16; ++c) {
        // M_c = exclusive running prefix (register state; overlaps loads)
        const size_t ub = ((size_t)bh * 16 + c) << 14;
#pragma unroll
        for (int mt = 0; mt < 2; ++mt)
#pragma unroll
            for (int nt = 0; nt < 2; ++nt) {
                int mtg = w * 2 + mt, ntg = slice * 2 + nt;
                int f0 = ntg * 2048 + (mtg >> 1) * 512 +
                         (l15 + ((mtg * 2 + (lq >> 1)) & 3) * 16) * 8 +
                         (lq & 1) * 4;
                half4 hv;
                hv[0] = (_Float16)accr[mt][nt][0];
                hv[1] = (_Float16)accr[mt][nt][1];
                hv[2] = (_Float16)accr[mt][nt][2];
                hv[3] = (_Float16)accr[mt][nt][3];
                *(half4*)&ut[ub + f0] = hv;
            }

        __syncthreads();   // prior chunk's frag reads complete
#pragma unroll
        for (int j = 0; j < 4; ++j)
#pragma unroll
            for (int i = 0; i < 8; ++i)
                Kt_s[(j * 4 + w) * 8 + i][lane] = kreg[j][i];
        *(uint4*)&Vt_s[tid >> 3][(tid & 7) * 8] = vreg;

        // issue next chunk's loads NOW; they fly during MFMA below
        if (c + 1 < 16) {
            const int n0 = (c + 1) * 64;
#pragma unroll
            for (int j = 0; j < 4; ++j)
                kreg[j] = *(const half8*)&kh[kbase + (size_t)(n0 + lane) * HD +
                                             (j * 4 + w) * 8];
            vreg = *(const uint4*)&vt[vbase + (size_t)(tid >> 3) * S +
                                      n0 + (tid & 7) * 8];
        }
        __syncthreads();

#pragma unroll
        for (int ks = 0; ks < 2; ++ks) {
            half8 afv[2], wfv[2];
#pragma unroll
            for (int mt = 0; mt < 2; ++mt)
                afv[mt] = *(const half8*)&Kt_s[(w * 2 + mt) * 16 + l15]
                                              [ks * 32 + lq * 8];
#pragma unroll
            for (int nt = 0; nt < 2; ++nt)
                wfv[nt] = *(const half8*)&Vt_s[nt * 16 + l15][ks * 32 + lq * 8];
#pragma unroll
            for (int mt = 0; mt < 2; ++mt)
#pragma unroll
                for (int nt = 0; nt < 2; ++nt)
                    accr[mt][nt] = __builtin_amdgcn_mfma_f32_16x16x32_f16(
                        afv[mt], wfv[nt], accr[mt][nt], 0, 0, 0);
        }
    }
}

// ---------------------------------------------------------------------------
// attn_local: O_tile = Q_tile . M^T_qt + tril(Q_tile K_qt^T) V_qt (verified).
// ---------------------------------------------------------------------------
__global__ __launch_bounds__(256) void attn_local(const _Float16* __restrict__ qh,
                                                  const _Float16* __restrict__ kh,
                                                  const _Float16* __restrict__ vt,
                                                  const _Float16* __restrict__ mt,
                                                  _Float16* __restrict__ o) {
    __shared__ _Float16 Ks[64][136];
    __shared__ _Float16 Vs[HD][72];
    __shared__ _Float16 Ps[64][72];
    __shared__ uint4 Ms[2048];

    const int qt = blockIdx.x;
    const int bh = blockIdx.y;
    const int b = bh >> 4, h = bh & 15;
    const int tid = threadIdx.x;
    const int lane = tid & 63;
    const int w = tid >> 6;
    const int l15 = lane & 15;
    const int lq = lane >> 4;
    const int qBase = qt * 64;
    const size_t sd_base = (size_t)bh * S * HD;

    half8 qf[4];
#pragma unroll
    for (int ks = 0; ks < 4; ++ks)
        qf[ks] = *(const half8*)&qh[sd_base + (size_t)(qBase + w * 16 + l15) * HD +
                                    ks * 32 + lq * 8];

    const _Float16* mtc = mt + (((size_t)bh * 16 + qt) << 14);
#pragma unroll
    for (int rr = 0; rr < 8; ++rr)
        gl_lds16(&mtc[(size_t)((rr * 4 + w) * 64 + lane) * 8],
                 &Ms[(rr * 4 + w) * 64]);

    uint4 pk[4], pv[4];
#pragma unroll
    for (int j = 0; j < 4; ++j) {
        int f = tid + j * 256;
        int rK = f >> 4, c8K = f & 15;
        int rV = f >> 3, c8V = f & 7;
        pk[j] = *(const uint4*)&kh[sd_base + (size_t)(qBase + rK) * HD + c8K * 8];
        pv[j] = *(const uint4*)&vt[sd_base + (size_t)rV * S + qBase + c8V * 8];
    }
#pragma unroll
    for (int j = 0; j < 4; ++j) {
        int f = tid + j * 256;
        int rK = f >> 4, c8K = f & 15;
        int rV = f >> 3, c8V = f & 7;
        *(uint4*)&Ks[rK][c8K * 8] = pk[j];
        *(uint4*)&Vs[rV][c8V * 8] = pv[j];
    }
    __syncthreads();

    f32x4 sacc[4];
#pragma unroll
    for (int nt = 0; nt < 4; ++nt)
        sacc[nt] = (f32x4){0.f, 0.f, 0.f, 0.f};
#pragma unroll
    for (int nt = 0; nt < 4; ++nt)
#pragma unroll
        for (int ks = 0; ks < 4; ++ks) {
            half8 kf = *(const half8*)&Ks[nt * 16 + l15][ks * 32 + lq * 8];
            sacc[nt] = __builtin_amdgcn_mfma_f32_16x16x32_f16(qf[ks], kf,
                                                              sacc[nt], 0, 0, 0);
        }

#pragma unroll
    for (int nt = 0; nt < 4; ++nt)
#pragma unroll
        for (int r = 0; r < 4; ++r) {
            int ql = w * 16 + lq * 4 + r;
            int kl = nt * 16 + l15;
            float sv = (kl <= ql) ? sacc[nt][r] : 0.f;
            Ps[ql][kl] = (_Float16)sv;
        }

    f32x4 oacc[8];
#pragma unroll
    for (int dt = 0; dt < 8; ++dt)
        oacc[dt] = (f32x4){0.f, 0.f, 0.f, 0.f};
#pragma unroll
    for (int dt = 0; dt < 8; ++dt)
#pragma unroll
        for (int km = 0; km < 4; ++km) {
            half8 mf = *(const half8*)&Ms[(dt * 4 + km) * 64 + lane];
            oacc[dt] = __builtin_amdgcn_mfma_f32_16x16x32_f16(qf[km], mf,
                                                              oacc[dt], 0, 0, 0);
        }
    __syncthreads();

    half8 pf[2];
    pf[0] = *(const half8*)&Ps[w * 16 + l15][lq * 8];
    pf[1] = *(const half8*)&Ps[w * 16 + l15][32 + lq * 8];
#pragma unroll
    for (int dt = 0; dt < 8; ++dt)
#pragma unroll
        for (int ks = 0; ks < 2; ++ks) {
            half8 vf = *(const half8*)&Vs[dt * 16 + l15][ks * 32 + lq * 8];
            oacc[dt] = __builtin_amdgcn_mfma_f32_16x16x32_f16(pf[ks], vf,
                                                              oacc[dt], 0, 0, 0);
        }

#pragma unroll
    for (int dt = 0; dt < 8; ++dt)
#pragma unroll
        for (int r = 0; r < 4; ++r)
            Ks[w * 16 + lq * 4 + r][dt * 16 + l15] = (_Float16)oacc[dt][r];
    __syncthreads();
#pragma unroll
    for (int j = 0; j < 4; ++j) {
        int f = tid + j * 256;
        int ql = f >> 4, c8 = f & 15;
        *(uint4*)&o[(size_t)(b * S + qBase + ql) * E + h * HD + c8 * 8] =
            *(const uint4*)&Ks[ql][c8 * 8];
    }
}

// ---------------------------------------------------------------------------
// Out-projection NT-GEMM, 128x128, double-buffered, BK=64 (verified r9).
// ---------------------------------------------------------------------------
__global__ __launch_bounds__(256) void gemm_out(const _Float16* __restrict__ A,
                                                const _Float16* __restrict__ Wp,
                                                float* __restrict__ C) {
    __shared__ uint4 As_l[2][1024];   // 2 x 16 KB
    __shared__ uint4 Ws_l[2][1024];   // 2 x 16 KB
    const int lid = (int)blockIdx.x;
    const int swz = (lid & 7) * 32 + (lid >> 3);
    const int gm  = swz >> 4;
    const int gn  = swz & 15;
    const int tid  = threadIdx.x;
    const int lane = tid & 63;
    const int w    = tid >> 6;
    const int wm   = (w >> 1) * 64;
    const int wn   = (w & 1) * 64;
    const int l15  = lane & 15;
    const int lq   = lane >> 4;
    const int mBase = gm * 128;
    const int nBase = gn * 128;
    const int wb64  = tid & 192;      // wave-uniform chunk base within 256

    f32x4 acc[4][4];
#pragma unroll
    for (int mt = 0; mt < 4; ++mt)
#pragma unroll
        for (int nt = 0; nt < 4; ++nt)
            acc[mt][nt] = (f32x4){0.f, 0.f, 0.f, 0.f};

    auto stage = [&](int bf, int k0) {
#pragma unroll
        for (int j = 0; j < 4; ++j) {
            int c  = j * 256 + tid;          // chunk 0..1023
            int rb = c >> 7;                 // 16-row block 0..7
            int q  = (c >> 4) & 7;           // 16B k-chunk 0..7
            int r  = c & 15;                 // row within block
            gl_lds16(&A[(size_t)(mBase + rb * 16 + r) * E + k0 + q * 8],
                     &As_l[bf][j * 256 + wb64]);
        }
#pragma unroll
        for (int j = 0; j < 4; ++j) {
            int c  = j * 256 + tid;
            int rb = c >> 7;
            int q  = (c >> 4) & 7;
            int r  = c & 15;
            gl_lds16(&Wp[(size_t)(nBase + rb * 16 + r) * E + k0 + q * 8],
                     &Ws_l[bf][j * 256 + wb64]);
        }
    };

    stage(0, 0);
    const int nIter = E / 64;                 // 32
    for (int it = 0; it < nIter; ++it) {
        __syncthreads();
        if (it + 1 < nIter) stage((it + 1) & 1, (it + 1) * 64);

        const int cur = it & 1;
        half8 af[4][2], wfr[4][2];
#pragma unroll
        for (int t = 0; t < 4; ++t)
#pragma unroll
            for (int ks = 0; ks < 2; ++ks) {
                int rbA = (wm >> 4) + t;
                int rbW = (wn >> 4) + t;
                af[t][ks]  = *(const half8*)&As_l[cur]
                    [rbA * 128 + (ks * 4 + lq) * 16 + l15];
                wfr[t][ks] = *(const half8*)&Ws_l[cur]
                    [rbW * 128 + (ks * 4 + lq) * 16 + l15];
            }
#pragma unroll
        for (int mt = 0; mt < 4; ++mt)
#pragma unroll
            for (int nt = 0; nt < 4; ++nt)
#pragma unroll
                for (int ks = 0; ks < 2; ++ks)
                    acc[mt][nt] = __builtin_amdgcn_mfma_f32_16x16x32_f16(
                        af[mt][ks], wfr[nt][ks], acc[mt][nt], 0, 0, 0);
    }

#pragma unroll
    for (int mt = 0; mt < 4; ++mt)
#pragma unroll
        for (int nt = 0; nt < 4; ++nt)
#pragma unroll
            for (int r = 0; r < 4; ++r) {
                int row = mBase + wm + mt * 16 + lq * 4 + r;
                int col = nBase + wn + nt * 16 + l15;
                C[(size_t)row * E + col] = acc[mt][nt][r];
            }
}

// ---------------------------------------------------------------------------
extern "C" void kernel_launch(void* const* d_in, const int* in_sizes, int n_in,
                              void* d_out, int out_size, void* d_ws, size_t ws_size,
                              hipStream_t stream) {
    (void)in_sizes; (void)n_in; (void)out_size; (void)ws_size;
    const float* hs = (const float*)d_in[0];
    const float* wq = (const float*)d_in[1];
    const float* wk = (const float*)d_in[2];
    const float* wv = (const float*)d_in[3];
    const float* wo = (const float*)d_in[4];
    const float* nc = (const float*)d_in[5];
    const float* am = (const float*)d_in[6];
    const int*  pos = (const int*)d_in[7];
    float* out = (float*)d_out;

    const size_t act = (size_t)B * S * E;           // 4,194,304 (== E*E)
    _Float16* hsb = (_Float16*)d_ws;                // fp16 copies
    _Float16* wqb = hsb + act;
    _Float16* wkb = wqb + act;
    _Float16* wvb = wkb + act;
    _Float16* wob = wvb + act;
    _Float16* qhh = wob + act;                      // Q (b,h,s,d)
    _Float16* khh = qhh + act;                      // K (b,h,s,d)
    _Float16* vtt = khh + act;                      // V^T (b,h,d,s)
    _Float16* abb = vtt + act;                      // attn out (b,s,E)
    _Float16* utm = wqb;                            // M frag-major (2 slots)
    float*    cnt = (float*)abb;                    // prefix counts (pre-attn)
    float*    tab = cnt + B * S;                    // rotary table, 512 KB
    // total ws: 9 * 8.39MB ~= 76 MB

    prep<<<2816 + B, 256, 0, stream>>>(
        hs, wq, wk, wv, wo, hsb, wqb, wkb, wvb, wob, am, pos, cnt, tab);

    gemm_qkv256<<<192, 512, 0, stream>>>(hsb, wqb, wkb, wvb,
                                         qhh, khh, vtt, am, nc, cnt, tab);

    kvp<<<dim3(4, B * H), 256, 0, stream>>>(khh, vtt, utm);

    attn_local<<<dim3(16, B * H), 256, 0, stream>>>(qhh, khh, vtt, utm, abb);

    gemm_out<<<256, 256, 0, stream>>>(abb, wob, out);
}